// Round 4
// baseline (586.793 us; speedup 1.0000x reference)
//
#include <hip/hip_runtime.h>
#include <hip/hip_cooperative_groups.h>

namespace cg = cooperative_groups;

// LengthAdaptor: B=16, T=512, C_IN=512, C_HID=256, C_EMB=384, K=5, MAX_DUR=8
// Outputs (concat, f32): x_up [16,4096,512] | ldp [16,512] | emb_up [16,4096,384]
//
// R13: cooperative mega-kernel. Phase bodies are verbatim R12 (proven 343us):
// conv_body with issue-early staging, x4-unrolled gathers, shfl LN rows.
// Structure: prep (normal dispatch) + ONE cooperative kernel (512 blk x 256
// thr = exactly 2 blocks/CU under launch_bounds(256,2), grid co-resident)
// with grid.sync() between phases:
//   P1: conv1 tile + x_up slice (order-mixed per block parity)
//   P2: ln1 rows + emb_up slice A
//   P3: conv2 tile + emb_up slice B (order-mixed)
//   P4: ln2+linear+mask
// Removes 3 dispatch boundaries and lets conv tails overlap gather work.

constexpr int Bn = 16, Tn = 512, CIN1 = 512, CHID = 256, CEMB = 384, MAXMEL = 4096;
constexpr int NROWS = Bn * Tn;
#define LRELU 0.3f
#define EPSV 1e-5f

typedef __attribute__((ext_vector_type(8))) short bf16x8;
typedef __attribute__((ext_vector_type(4))) float f32x4;
typedef __attribute__((ext_vector_type(16))) float f32x16;
typedef __attribute__((ext_vector_type(4))) unsigned int u32x4;
typedef unsigned short ushort_t;

static __device__ __forceinline__ ushort_t f2bf(float f) {
  unsigned u = __builtin_bit_cast(unsigned, f);
  unsigned r = (u + 0x7fffu + ((u >> 16) & 1u)) >> 16;  // RNE
  return (ushort_t)r;
}

// ---------------------------------------------------------------------------
// Conv MFMA body (32x32x16), verbatim R12. Block tile 32 rows x 128 cols,
// 4 waves. A staged per 128-ci chunk in LDS (XOR swizzle), issue-early
// staging; B direct from L2 (fragment-contiguous). Writes pre-act f32 hraw.
// ---------------------------------------------------------------------------
template <int CI, bool F32IN>
static __device__ __forceinline__ void conv_body(
    int mt, int ns,
    const float* __restrict__ xin, const ushort_t* __restrict__ inbf,
    const ushort_t* __restrict__ wB, float* __restrict__ hraw) {
  constexpr int NCHUNK = CI / 128;
  constexpr int ROWS = 36, LDSTRIDE = 136;
  __shared__ ushort_t sA[ROWS * LDSTRIDE];

  const int b = mt >> 4, t0 = (mt & 15) * 32;
  const int tid = threadIdx.x;
  const int l = tid & 63, nh = tid >> 6;
  const int lm = l & 31, lq = l >> 5;
  const int cob32 = ns * 4 + nh;

  f32x16 acc;
#pragma unroll
  for (int i = 0; i < 16; ++i) acc[i] = 0.f;

  const ushort_t* pB = wB + (size_t)cob32 * 512 + l * 8;

  const int rbase = tid >> 6;           // p = i*256+tid -> r = i*4 + (tid>>6)
  const int c2 = (tid & 63) * 2;

#pragma unroll 1
  for (int chunk = 0; chunk < NCHUNK; ++chunk) {
    {
      const int cibase = chunk * 128;
      float2 rf[9];
      unsigned ru[9];
      // issue phase: all 9 loads in flight
#pragma unroll
      for (int i = 0; i < 9; ++i) {
        const int r = i * 4 + rbase;
        const int t = t0 - 2 + r;
        if (F32IN) {
          rf[i] = make_float2(0.f, 0.f);
          if ((unsigned)t < (unsigned)Tn)
            rf[i] = *(const float2*)(xin + (size_t)(b * Tn + t) * CI + cibase + c2);
        } else {
          ru[i] = 0u;
          if ((unsigned)t < (unsigned)Tn)
            ru[i] = *(const unsigned*)(inbf + (size_t)(b * Tn + t) * CI + cibase + c2);
        }
      }
      // write phase: cvt + swizzled LDS write
#pragma unroll
      for (int i = 0; i < 9; ++i) {
        const int r = i * 4 + rbase;
        unsigned hv;
        if (F32IN)
          hv = (unsigned)f2bf(rf[i].x) | ((unsigned)f2bf(rf[i].y) << 16);
        else
          hv = ru[i];
        const int sw = ((r >> 3) & 3) << 3;
        *(unsigned*)&sA[r * LDSTRIDE + (c2 ^ sw)] = hv;
      }
    }
    __syncthreads();

#pragma unroll 1
    for (int ksh = 0; ksh < 5; ++ksh) {
      const int r = lm + ksh;
      const int sw = ((r >> 3) & 3) << 3;
      const size_t bbase = (size_t)((ksh * (CI / 16) + chunk * 8) * 8) * 512;
#pragma unroll
      for (int kk = 0; kk < 8; ++kk) {
        const int c = (kk * 16 + lq * 8) ^ sw;
        const bf16x8 a = *(const bf16x8*)&sA[r * LDSTRIDE + c];
        const bf16x8 bv = *(const bf16x8*)(pB + bbase + (size_t)kk * 8 * 512);
        acc = __builtin_amdgcn_mfma_f32_32x32x16_bf16(a, bv, acc, 0, 0, 0);
      }
    }
    __syncthreads();
  }

  // D: col = lane&31, row = (reg&3) + 8*(reg>>2) + 4*(lane>>5)
  const int col = ns * 128 + nh * 32 + lm;
  float* pOut = hraw + (size_t)(b * Tn + t0) * 256 + col;
#pragma unroll
  for (int reg = 0; reg < 16; ++reg) {
    const int row = (reg & 3) + 8 * (reg >> 2) + 4 * lq;
    pOut[(size_t)row * 256] = acc[reg];
  }
}

// ---------------------------------------------------------------------------
// x_up gather slice: 16384 f32x4 units per block (contiguous 256KB region),
// x4-unrolled (R12b). 512 blocks cover 8,388,608 units exactly.
// ---------------------------------------------------------------------------
static __device__ __forceinline__ void xup_slice(
    int cid, const float* __restrict__ x, const int* __restrict__ idx,
    float* __restrict__ x_up) {
  const f32x4* x4 = (const f32x4*)x;
  f32x4* xu4 = (f32x4*)x_up;
  const int base = cid * 16384 + threadIdx.x;
  const f32x4 z = (f32x4){0.f, 0.f, 0.f, 0.f};
#pragma unroll 1
  for (int k0 = 0; k0 < 64; k0 += 4) {
    int tv[4];
#pragma unroll
    for (int j = 0; j < 4; ++j)
      tv[j] = idx[(base + (k0 + j) * 256) >> 7];
    f32x4 v[4];
#pragma unroll
    for (int j = 0; j < 4; ++j) {
      const int u = base + (k0 + j) * 256;
      const int i = u & 127;
      const int b = u >> 19;              // (u>>7)>>12
      v[j] = (tv[j] >= 0) ? x4[((b << 9) + tv[j]) * 128 + i] : z;
    }
#pragma unroll
    for (int j = 0; j < 4; ++j)
      __builtin_nontemporal_store(v[j], &xu4[base + (k0 + j) * 256]);
  }
}

// ---------------------------------------------------------------------------
// emb_up gather slice: units u = cid*12288 + k*256 + tid, k in [klo,khi).
// Full range k in [0,48): 512 blocks cover 6,291,456 units exactly.
// ---------------------------------------------------------------------------
static __device__ __forceinline__ void emb_slice(
    int cid, int klo, int khi, const float* __restrict__ emb,
    const int* __restrict__ idx, float* __restrict__ emb_up) {
  const f32x4* e4 = (const f32x4*)emb;
  f32x4* eu4 = (f32x4*)emb_up;
  const int base = cid * 12288 + threadIdx.x;
  const f32x4 z = (f32x4){0.f, 0.f, 0.f, 0.f};
#pragma unroll 1
  for (int k0 = klo; k0 < khi; k0 += 4) {
    int tv[4], bp[4];
#pragma unroll
    for (int j = 0; j < 4; ++j) {
      const int u = base + (k0 + j) * 256;
      bp[j] = u / 96;
      tv[j] = idx[bp[j]];
    }
    f32x4 v[4];
#pragma unroll
    for (int j = 0; j < 4; ++j) {
      const int u = base + (k0 + j) * 256;
      const int i = u - bp[j] * 96;
      const int b = bp[j] >> 12;
      v[j] = (tv[j] >= 0) ? e4[((b << 9) + tv[j]) * 96 + i] : z;
    }
#pragma unroll
    for (int j = 0; j < 4; ++j)
      __builtin_nontemporal_store(v[j], &eu4[base + (k0 + j) * 256]);
  }
}

// ---------------------------------------------------------------------------
// LN rows: 16 rows per block (4 passes x 4 waves), body verbatim R12.
// ---------------------------------------------------------------------------
template <bool FINAL>
static __device__ __forceinline__ void ln_rows(
    int cid, const float* __restrict__ hraw,
    const float* __restrict__ bias, const float* __restrict__ g,
    const float* __restrict__ be, ushort_t* __restrict__ h1,
    const float* __restrict__ lw, const float* __restrict__ lb,
    const unsigned char* __restrict__ mask, float* __restrict__ ldp) {
  const int l = threadIdx.x & 63;
#pragma unroll 1
  for (int pass = 0; pass < 4; ++pass) {
    const int row = cid * 16 + pass * 4 + (threadIdx.x >> 6);
    const f32x4 p = ((const f32x4*)hraw)[row * 64 + l];
    const f32x4 bi = ((const f32x4*)bias)[l];
    float v0 = p.x + bi.x, v1 = p.y + bi.y, v2 = p.z + bi.z, v3 = p.w + bi.w;
    v0 = (v0 > 0.f) ? v0 : LRELU * v0;
    v1 = (v1 > 0.f) ? v1 : LRELU * v1;
    v2 = (v2 > 0.f) ? v2 : LRELU * v2;
    v3 = (v3 > 0.f) ? v3 : LRELU * v3;
    float s = v0 + v1 + v2 + v3;
    float s2 = v0 * v0 + v1 * v1 + v2 * v2 + v3 * v3;
#pragma unroll
    for (int off = 32; off >= 1; off >>= 1) {
      s += __shfl_xor(s, off);
      s2 += __shfl_xor(s2, off);
    }
    const float mu = s * (1.f / 256.f);
    const float var = s2 * (1.f / 256.f) - mu * mu;
    const float rs = rsqrtf(var + EPSV);
    const f32x4 gg = ((const f32x4*)g)[l];
    const f32x4 bb = ((const f32x4*)be)[l];
    const float h0 = (v0 - mu) * rs * gg.x + bb.x;
    const float h1v = (v1 - mu) * rs * gg.y + bb.y;
    const float h2 = (v2 - mu) * rs * gg.z + bb.z;
    const float h3 = (v3 - mu) * rs * gg.w + bb.w;
    if (!FINAL) {
      ushort4 uh;
      uh.x = f2bf(h0); uh.y = f2bf(h1v); uh.z = f2bf(h2); uh.w = f2bf(h3);
      ((ushort4*)h1)[row * 64 + l] = uh;
    } else {
      const f32x4 lv = ((const f32x4*)lw)[l];
      float d = h0 * lv.x + h1v * lv.y + h2 * lv.z + h3 * lv.w;
#pragma unroll
      for (int off = 32; off >= 1; off >>= 1) d += __shfl_xor(d, off);
      if (l == 0) {
        float val = d + lb[0];
        if (mask[row]) val = 0.f;
        ldp[row] = val;
      }
    }
  }
}

// ---------------------------------------------------------------------------
// Cooperative mega-kernel: 512 blocks x 256 threads, all co-resident
// (2 blocks/CU, VGPR <= 256 via launch_bounds(256,2)).
// ---------------------------------------------------------------------------
__global__ __launch_bounds__(256, 2) void mega_kernel(
    const float* __restrict__ x_res, const ushort_t* __restrict__ w1,
    float* __restrict__ hraw,
    const float* __restrict__ x, const int* __restrict__ idx,
    float* __restrict__ x_up,
    const float* __restrict__ c1b, const float* __restrict__ g1,
    const float* __restrict__ b1, ushort_t* __restrict__ h1,
    const float* __restrict__ emb, float* __restrict__ emb_up,
    const ushort_t* __restrict__ w2, const float* __restrict__ c2b,
    const float* __restrict__ g2, const float* __restrict__ b2,
    const float* __restrict__ lw, const float* __restrict__ lb,
    const unsigned char* __restrict__ mask, float* __restrict__ ldp) {
  cg::grid_group grid = cg::this_grid();
  const int cid = blockIdx.x;
  // parity robust to either block->CU pairing convention (i,i+256) or (2i,2i+1)
  const bool gfirst = (((cid >> 8) ^ cid) & 1) != 0;

  // ---- Phase 1: conv1 tile + x_up slice ----
  if (gfirst) {
    xup_slice(cid, x, idx, x_up);
    conv_body<512, true>(cid & 255, cid >> 8, x_res, nullptr, w1, hraw);
  } else {
    conv_body<512, true>(cid & 255, cid >> 8, x_res, nullptr, w1, hraw);
    xup_slice(cid, x, idx, x_up);
  }
  grid.sync();

  // ---- Phase 2: ln1 rows + emb_up slice A (k 0..32) ----
  if (gfirst) {
    emb_slice(cid, 0, 32, emb, idx, emb_up);
    ln_rows<false>(cid, hraw, c1b, g1, b1, h1, nullptr, nullptr, nullptr, nullptr);
  } else {
    ln_rows<false>(cid, hraw, c1b, g1, b1, h1, nullptr, nullptr, nullptr, nullptr);
    emb_slice(cid, 0, 32, emb, idx, emb_up);
  }
  grid.sync();

  // ---- Phase 3: conv2 tile + emb_up slice B (k 32..48) ----
  if (gfirst) {
    emb_slice(cid, 32, 48, emb, idx, emb_up);
    conv_body<256, false>(cid & 255, cid >> 8, nullptr, h1, w2, hraw);
  } else {
    conv_body<256, false>(cid & 255, cid >> 8, nullptr, h1, w2, hraw);
    emb_slice(cid, 32, 48, emb, idx, emb_up);
  }
  grid.sync();

  // ---- Phase 4: ln2 + linear + mask -> ldp ----
  ln_rows<true>(cid, hraw, c2b, g2, b2, nullptr, lw, lb, mask, ldp);
}

// ---------------------------------------------------------------------------
// Dispatch 1: weight prep (blocks 0..239, 8 frags/block) + build_idx
// (blocks 240..255). 512 threads. Verbatim R9/R12.
// ---------------------------------------------------------------------------
__global__ __launch_bounds__(512) void prep_kernel(
    const float* __restrict__ w1src, const float* __restrict__ w2src,
    ushort_t* __restrict__ w1dst, ushort_t* __restrict__ w2dst,
    const int* __restrict__ dur, int* __restrict__ idx) {
  __shared__ int wsum[8];
  const int blk = blockIdx.x;
  const int tid = threadIdx.x;
  if (blk < 240) {
    const float* src;
    ushort_t* dst;
    int CI, fr, sh;
    const int wv = tid >> 6, l = tid & 63;
    if (blk < 160) { src = w1src; dst = w1dst; CI = 512; sh = 5; fr = blk * 8 + wv; }
    else           { src = w2src; dst = w2dst; CI = 256; sh = 4; fr = (blk - 160) * 8 + wv; }
    const int cob32 = fr & 7;
    const int t = fr >> 3;
    const int ksh = t >> sh;
    const int ci16 = t & ((1 << sh) - 1);
    const int ci = ci16 * 16 + (l >> 5) * 8;
    const int co = cob32 * 32 + (l & 31);
    ushort_t v[8];
#pragma unroll
    for (int j = 0; j < 8; ++j)
      v[j] = f2bf(src[((size_t)(ksh * CI + ci + j)) * 256 + co]);
    u32x4 pack;
#pragma unroll
    for (int q = 0; q < 4; ++q)
      pack[q] = (unsigned)v[q * 2] | ((unsigned)v[q * 2 + 1] << 16);
    *(u32x4*)&dst[(size_t)fr * 512 + l * 8] = pack;
    return;
  }
  // ---- build_idx path ----
  const int b = blk - 240;
  const int lane = tid & 63, wv = tid >> 6;
  const int d = dur[b * Tn + tid];
  int v = d;
#pragma unroll
  for (int off = 1; off <= 32; off <<= 1) {
    const int t = __shfl_up(v, off);
    if (lane >= off) v += t;
  }
  if (lane == 63) wsum[wv] = v;
  __syncthreads();
  int woff = 0, total = 0;
#pragma unroll
  for (int i = 0; i < 8; ++i) {
    const int s = wsum[i];
    if (i < wv) woff += s;
    total += s;
  }
  const int end = v + woff;               // inclusive cumsum
  for (int p = end - d; p < end; ++p) idx[b * MAXMEL + p] = tid;
  for (int p = total + tid; p < MAXMEL; p += 512) idx[b * MAXMEL + p] = -1;
}

// ---------------------------------------------------------------------------
extern "C" void kernel_launch(void* const* d_in, const int* in_sizes, int n_in,
                              void* d_out, int out_size, void* d_ws, size_t ws_size,
                              hipStream_t stream) {
  const float* x     = (const float*)d_in[0];
  const float* x_res = (const float*)d_in[1];
  const int*   dur   = (const int*)d_in[2];
  const float* emb   = (const float*)d_in[3];
  const unsigned char* mask = (const unsigned char*)d_in[4];
  const float* c1w = (const float*)d_in[5];
  const float* c1b = (const float*)d_in[6];
  const float* g1  = (const float*)d_in[7];
  const float* b1  = (const float*)d_in[8];
  const float* c2w = (const float*)d_in[9];
  const float* c2b = (const float*)d_in[10];
  const float* g2  = (const float*)d_in[11];
  const float* b2  = (const float*)d_in[12];
  const float* lw  = (const float*)d_in[13];
  const float* lb  = (const float*)d_in[14];

  float* x_up   = (float*)d_out;
  float* ldp    = x_up + (size_t)Bn * MAXMEL * CIN1;
  float* emb_up = ldp + (size_t)Bn * Tn;

  // ws layout: idx 256KB | h1 4MB | w1 1.31MB | w2 0.66MB | hraw 8MB ≈ 14.5MB
  int* idx = (int*)d_ws;
  ushort_t* h1 = (ushort_t*)((char*)d_ws + (size_t)Bn * MAXMEL * 4);
  ushort_t* w1 = h1 + (size_t)NROWS * 256;
  ushort_t* w2 = w1 + (size_t)5 * 512 * 256;
  float* hraw = (float*)(w2 + (size_t)5 * 256 * 256);

  prep_kernel<<<256, 512, 0, stream>>>(c1w, c2w, w1, w2, dur, idx);

  void* args[] = {
      (void*)&x_res, (void*)&w1, (void*)&hraw, (void*)&x, (void*)&idx,
      (void*)&x_up, (void*)&c1b, (void*)&g1, (void*)&b1, (void*)&h1,
      (void*)&emb, (void*)&emb_up, (void*)&w2, (void*)&c2b, (void*)&g2,
      (void*)&b2, (void*)&lw, (void*)&lb, (void*)&mask, (void*)&ldp};
  hipLaunchCooperativeKernel((const void*)mega_kernel, dim3(512), dim3(256),
                             args, 0, stream);
}

// Round 5
// 355.091 us; speedup vs baseline: 1.6525x; 1.6525x over previous
//
#include <hip/hip_runtime.h>

// LengthAdaptor: B=16, T=512, C_IN=512, C_HID=256, C_EMB=384, K=5, MAX_DUR=8
// Outputs (concat, f32): x_up [16,4096,512] | ldp [16,512] | emb_up [16,4096,384]
//
// R14: 3 dispatches, no grid.sync (R13 lesson: grid.sync ~100us on gfx950).
//  D1 prep (verbatim R12)
//  D2 conv1+bias+lrelu+LN1 -> h1 bf16 (fused, 256 full-row tiles) + x_up
//     gather (1024 blocks, verbatim R12), grid 1280, 1:4 interleave, (256,2)
//  D3 conv2+bias+lrelu+LN2+linear+mask -> ldp (fused) + emb_up gather, same.
// Fused conv = R11's verified 256-thr dual-chain full-row body + R12's
// issue-early staging. Deletes both ln dispatches and both hraw round-trips
// (-2 boundaries, -33.6MB HBM) while keeping R12's proven gather occupancy.

constexpr int Bn = 16, Tn = 512, CIN1 = 512, CHID = 256, CEMB = 384, MAXMEL = 4096;
constexpr int NROWS = Bn * Tn;
#define LRELU 0.3f
#define EPSV 1e-5f

typedef __attribute__((ext_vector_type(8))) short bf16x8;
typedef __attribute__((ext_vector_type(4))) float f32x4;
typedef __attribute__((ext_vector_type(16))) float f32x16;
typedef __attribute__((ext_vector_type(4))) unsigned int u32x4;
typedef unsigned short ushort_t;

static __device__ __forceinline__ ushort_t f2bf(float f) {
  unsigned u = __builtin_bit_cast(unsigned, f);
  unsigned r = (u + 0x7fffu + ((u >> 16) & 1u)) >> 16;  // RNE
  return (ushort_t)r;
}

// ---------------------------------------------------------------------------
// Fused conv (32x32x16) + bias + leakyrelu + LN [+ linear+mask].
// 256 threads = 4 waves; tile 32 rows x 256 cols; wave nh owns col chains
// cob32 = nh and nh+4 (cols nh*32.. and 128+nh*32..). A staged per 128-ci
// chunk in XOR-swizzled LDS with R12 issue-early staging; B direct from L2.
// Epilogue: per-wave 32-lane shfl reduce + cross-wave LDS reduce (R11 body).
// ---------------------------------------------------------------------------
template <int CI, bool F32IN, bool FINAL>
static __device__ __forceinline__ void conv_fused_body(
    int mt,
    const float* __restrict__ xin, const ushort_t* __restrict__ inbf,
    const ushort_t* __restrict__ wB,
    const float* __restrict__ bias, const float* __restrict__ g,
    const float* __restrict__ be, ushort_t* __restrict__ h1out,
    const float* __restrict__ lw, const float* __restrict__ lb,
    const unsigned char* __restrict__ mask, float* __restrict__ ldp) {
  constexpr int NCHUNK = CI / 128;
  constexpr int ROWS = 36, LDSTRIDE = 136;
  __shared__ ushort_t sA[ROWS * LDSTRIDE];
  __shared__ float sred[32][4];
  __shared__ float s2red[32][4];
  __shared__ float smu[32];
  __shared__ float srs[32];

  const int b = mt >> 4, t0 = (mt & 15) * 32;
  const int tid = threadIdx.x;
  const int l = tid & 63, nh = tid >> 6;      // wave 0..3
  const int lm = l & 31, lq = l >> 5;

  f32x16 acc0, acc1;
#pragma unroll
  for (int i = 0; i < 16; ++i) { acc0[i] = 0.f; acc1[i] = 0.f; }

  const ushort_t* pB0 = wB + (size_t)nh * 512 + l * 8;        // cob32 = nh
  const ushort_t* pB1 = wB + (size_t)(nh + 4) * 512 + l * 8;  // cob32 = nh+4

  const int rbase = tid >> 6;           // p = i*256+tid -> r = i*4 + (tid>>6)
  const int c2 = (tid & 63) * 2;

#pragma unroll 1
  for (int chunk = 0; chunk < NCHUNK; ++chunk) {
    {
      const int cibase = chunk * 128;
      float2 rf[9];
      unsigned ru[9];
      // issue phase: all 9 loads in flight (R12a)
#pragma unroll
      for (int i = 0; i < 9; ++i) {
        const int r = i * 4 + rbase;
        const int t = t0 - 2 + r;
        if (F32IN) {
          rf[i] = make_float2(0.f, 0.f);
          if ((unsigned)t < (unsigned)Tn)
            rf[i] = *(const float2*)(xin + (size_t)(b * Tn + t) * CI + cibase + c2);
        } else {
          ru[i] = 0u;
          if ((unsigned)t < (unsigned)Tn)
            ru[i] = *(const unsigned*)(inbf + (size_t)(b * Tn + t) * CI + cibase + c2);
        }
      }
      // write phase: cvt + swizzled LDS write
#pragma unroll
      for (int i = 0; i < 9; ++i) {
        const int r = i * 4 + rbase;
        unsigned hv;
        if (F32IN)
          hv = (unsigned)f2bf(rf[i].x) | ((unsigned)f2bf(rf[i].y) << 16);
        else
          hv = ru[i];
        const int sw = ((r >> 3) & 3) << 3;
        *(unsigned*)&sA[r * LDSTRIDE + (c2 ^ sw)] = hv;
      }
    }
    __syncthreads();

#pragma unroll 1
    for (int ksh = 0; ksh < 5; ++ksh) {
      const int r = lm + ksh;
      const int sw = ((r >> 3) & 3) << 3;
      const size_t bbase = (size_t)((ksh * (CI / 16) + chunk * 8) * 8) * 512;
#pragma unroll
      for (int kk = 0; kk < 8; ++kk) {
        const int c = (kk * 16 + lq * 8) ^ sw;
        const bf16x8 a = *(const bf16x8*)&sA[r * LDSTRIDE + c];
        const bf16x8 bv0 = *(const bf16x8*)(pB0 + bbase + (size_t)kk * 8 * 512);
        const bf16x8 bv1 = *(const bf16x8*)(pB1 + bbase + (size_t)kk * 8 * 512);
        acc0 = __builtin_amdgcn_mfma_f32_32x32x16_bf16(a, bv0, acc0, 0, 0, 0);
        acc1 = __builtin_amdgcn_mfma_f32_32x32x16_bf16(a, bv1, acc1, 0, 0, 0);
      }
    }
    __syncthreads();
  }

  // ---- epilogue: bias + leakyrelu + LN(256) [+ linear + mask] (R11 body) ----
  // chain0 cols: nh*32 + lm ; chain1 cols: 128 + nh*32 + lm
  const int col0 = nh * 32 + lm;
  const int col1 = col0 + 128;
  const float bi0 = bias[col0], bi1 = bias[col1];
  float s[16], s2v[16];
#pragma unroll
  for (int rg = 0; rg < 16; ++rg) {
    float a0 = acc0[rg] + bi0;
    float a1 = acc1[rg] + bi1;
    a0 = (a0 > 0.f) ? a0 : LRELU * a0;
    a1 = (a1 > 0.f) ? a1 : LRELU * a1;
    acc0[rg] = a0;
    acc1[rg] = a1;
    s[rg] = a0 + a1;
    s2v[rg] = a0 * a0 + a1 * a1;
  }
#pragma unroll
  for (int off = 16; off >= 1; off >>= 1) {
#pragma unroll
    for (int rg = 0; rg < 16; ++rg) {
      s[rg] += __shfl_xor(s[rg], off);
      s2v[rg] += __shfl_xor(s2v[rg], off);
    }
  }
  if (lm == 0) {
#pragma unroll
    for (int rg = 0; rg < 16; ++rg) {
      const int row = (rg & 3) + 8 * (rg >> 2) + 4 * lq;
      sred[row][nh] = s[rg];
      s2red[row][nh] = s2v[rg];
    }
  }
  __syncthreads();
  if (tid < 32) {
    float a = 0.f, q = 0.f;
#pragma unroll
    for (int w = 0; w < 4; ++w) { a += sred[tid][w]; q += s2red[tid][w]; }
    const float mu = a * (1.f / 256.f);
    const float var = q * (1.f / 256.f) - mu * mu;
    smu[tid] = mu;
    srs[tid] = rsqrtf(var + EPSV);
  }
  __syncthreads();

  const float g0 = g[col0], g1v = g[col1];
  const float be0 = be[col0], be1 = be[col1];
  if constexpr (!FINAL) {
    ushort_t* po = h1out + (size_t)(b * Tn + t0) * 256;
#pragma unroll
    for (int rg = 0; rg < 16; ++rg) {
      const int row = (rg & 3) + 8 * (rg >> 2) + 4 * lq;
      const float mu = smu[row], rs = srs[row];
      po[(size_t)row * 256 + col0] = f2bf((acc0[rg] - mu) * rs * g0 + be0);
      po[(size_t)row * 256 + col1] = f2bf((acc1[rg] - mu) * rs * g1v + be1);
    }
  } else {
    const float w0 = lw[col0], w1v = lw[col1];
    float d[16];
#pragma unroll
    for (int rg = 0; rg < 16; ++rg) {
      const int row = (rg & 3) + 8 * (rg >> 2) + 4 * lq;
      const float mu = smu[row], rs = srs[row];
      const float h0 = (acc0[rg] - mu) * rs * g0 + be0;
      const float h1v = (acc1[rg] - mu) * rs * g1v + be1;
      d[rg] = h0 * w0 + h1v * w1v;
    }
#pragma unroll
    for (int off = 16; off >= 1; off >>= 1) {
#pragma unroll
      for (int rg = 0; rg < 16; ++rg) d[rg] += __shfl_xor(d[rg], off);
    }
    __syncthreads();                         // sred free for reuse
    if (lm == 0) {
#pragma unroll
      for (int rg = 0; rg < 16; ++rg) {
        const int row = (rg & 3) + 8 * (rg >> 2) + 4 * lq;
        sred[row][nh] = d[rg];
      }
    }
    __syncthreads();
    if (tid < 32) {
      float a = lb[0];
#pragma unroll
      for (int w = 0; w < 4; ++w) a += sred[tid][w];
      const int grow = b * Tn + t0 + tid;
      ldp[grow] = mask[grow] ? 0.f : a;
    }
  }
}

// ---------------------------------------------------------------------------
// Dispatch 2: fused conv1+ln1 (blk%5==0, 256 blocks) + x_up gather (1024
// blocks, verbatim R12 x4-unrolled). Grid 1280.
// ---------------------------------------------------------------------------
__global__ __launch_bounds__(256, 2) void conv1_gather_kernel(
    const float* __restrict__ x_res, const ushort_t* __restrict__ w1,
    const float* __restrict__ c1b, const float* __restrict__ g1,
    const float* __restrict__ b1, ushort_t* __restrict__ h1,
    const float* __restrict__ x, const int* __restrict__ idx,
    float* __restrict__ x_up) {
  const int blk = blockIdx.x;
  if (blk % 5 == 0) {
    conv_fused_body<512, true, false>(blk / 5, x_res, nullptr, w1, c1b, g1, b1,
                                      h1, nullptr, nullptr, nullptr, nullptr);
    return;
  }
  // ---- x_up gather: 1024 blocks, 8,388,608 f32x4 units = 32 iters exact ----
  const int gid = blk - 1 - blk / 5;      // 0..1023
  const f32x4* x4 = (const f32x4*)x;
  f32x4* xu4 = (f32x4*)x_up;
  const int tid0 = gid * 256 + threadIdx.x;
  constexpr int stride = 1024 * 256;
  const f32x4 z = (f32x4){0.f, 0.f, 0.f, 0.f};
#pragma unroll 1
  for (int k0 = 0; k0 < 32; k0 += 4) {
    int tv[4];
#pragma unroll
    for (int j = 0; j < 4; ++j)
      tv[j] = idx[(tid0 + (k0 + j) * stride) >> 7];
    f32x4 v[4];
#pragma unroll
    for (int j = 0; j < 4; ++j) {
      const int u = tid0 + (k0 + j) * stride;
      const int i = u & 127;
      const int b = u >> 19;              // (u>>7)>>12
      v[j] = (tv[j] >= 0) ? x4[((b << 9) + tv[j]) * 128 + i] : z;
    }
#pragma unroll
    for (int j = 0; j < 4; ++j)
      __builtin_nontemporal_store(v[j], &xu4[tid0 + (k0 + j) * stride]);
  }
}

// ---------------------------------------------------------------------------
// Dispatch 3: fused conv2+ln2+linear+mask (blk%5==0, 256 blocks) + emb_up
// gather (1024 blocks, verbatim R12). Grid 1280.
// ---------------------------------------------------------------------------
__global__ __launch_bounds__(256, 2) void conv2_gather_kernel(
    const ushort_t* __restrict__ h1, const ushort_t* __restrict__ w2,
    const float* __restrict__ c2b, const float* __restrict__ g2,
    const float* __restrict__ b2, const float* __restrict__ lw,
    const float* __restrict__ lb, const unsigned char* __restrict__ mask,
    float* __restrict__ ldp,
    const float* __restrict__ emb, const int* __restrict__ idx,
    float* __restrict__ emb_up) {
  const int blk = blockIdx.x;
  if (blk % 5 == 0) {
    conv_fused_body<256, false, true>(blk / 5, nullptr, h1, w2, c2b, g2, b2,
                                      nullptr, lw, lb, mask, ldp);
    return;
  }
  // ---- emb_up gather: 1024 blocks, 6,291,456 f32x4 units = 24 iters exact ----
  const int gid = blk - 1 - blk / 5;
  const f32x4* e4 = (const f32x4*)emb;
  f32x4* eu4 = (f32x4*)emb_up;
  const int tid0 = gid * 256 + threadIdx.x;
  constexpr int stride = 1024 * 256;
  const f32x4 z = (f32x4){0.f, 0.f, 0.f, 0.f};
#pragma unroll 1
  for (int k0 = 0; k0 < 24; k0 += 4) {
    int tv[4];
    int bp[4];
#pragma unroll
    for (int j = 0; j < 4; ++j) {
      const int u = tid0 + (k0 + j) * stride;
      bp[j] = u / 96;
      tv[j] = idx[bp[j]];
    }
    f32x4 v[4];
#pragma unroll
    for (int j = 0; j < 4; ++j) {
      const int u = tid0 + (k0 + j) * stride;
      const int i = u - bp[j] * 96;
      const int b = bp[j] >> 12;
      v[j] = (tv[j] >= 0) ? e4[((b << 9) + tv[j]) * 96 + i] : z;
    }
#pragma unroll
    for (int j = 0; j < 4; ++j)
      __builtin_nontemporal_store(v[j], &eu4[tid0 + (k0 + j) * stride]);
  }
}

// ---------------------------------------------------------------------------
// Dispatch 1: weight prep (blocks 0..239, 8 frags/block) + build_idx
// (blocks 240..255). 512 threads. Verbatim R12.
// ---------------------------------------------------------------------------
__global__ __launch_bounds__(512) void prep_kernel(
    const float* __restrict__ w1src, const float* __restrict__ w2src,
    ushort_t* __restrict__ w1dst, ushort_t* __restrict__ w2dst,
    const int* __restrict__ dur, int* __restrict__ idx) {
  __shared__ int wsum[8];
  const int blk = blockIdx.x;
  const int tid = threadIdx.x;
  if (blk < 240) {
    const float* src;
    ushort_t* dst;
    int CI, fr, sh;
    const int wv = tid >> 6, l = tid & 63;
    if (blk < 160) { src = w1src; dst = w1dst; CI = 512; sh = 5; fr = blk * 8 + wv; }
    else           { src = w2src; dst = w2dst; CI = 256; sh = 4; fr = (blk - 160) * 8 + wv; }
    const int cob32 = fr & 7;
    const int t = fr >> 3;
    const int ksh = t >> sh;
    const int ci16 = t & ((1 << sh) - 1);
    const int ci = ci16 * 16 + (l >> 5) * 8;
    const int co = cob32 * 32 + (l & 31);
    ushort_t v[8];
#pragma unroll
    for (int j = 0; j < 8; ++j)
      v[j] = f2bf(src[((size_t)(ksh * CI + ci + j)) * 256 + co]);
    u32x4 pack;
#pragma unroll
    for (int q = 0; q < 4; ++q)
      pack[q] = (unsigned)v[q * 2] | ((unsigned)v[q * 2 + 1] << 16);
    *(u32x4*)&dst[(size_t)fr * 512 + l * 8] = pack;
    return;
  }
  // ---- build_idx path ----
  const int b = blk - 240;
  const int lane = tid & 63, wv = tid >> 6;
  const int d = dur[b * Tn + tid];
  int v = d;
#pragma unroll
  for (int off = 1; off <= 32; off <<= 1) {
    const int t = __shfl_up(v, off);
    if (lane >= off) v += t;
  }
  if (lane == 63) wsum[wv] = v;
  __syncthreads();
  int woff = 0, total = 0;
#pragma unroll
  for (int i = 0; i < 8; ++i) {
    const int s = wsum[i];
    if (i < wv) woff += s;
    total += s;
  }
  const int end = v + woff;               // inclusive cumsum
  for (int p = end - d; p < end; ++p) idx[b * MAXMEL + p] = tid;
  for (int p = total + tid; p < MAXMEL; p += 512) idx[b * MAXMEL + p] = -1;
}

// ---------------------------------------------------------------------------
extern "C" void kernel_launch(void* const* d_in, const int* in_sizes, int n_in,
                              void* d_out, int out_size, void* d_ws, size_t ws_size,
                              hipStream_t stream) {
  const float* x     = (const float*)d_in[0];
  const float* x_res = (const float*)d_in[1];
  const int*   dur   = (const int*)d_in[2];
  const float* emb   = (const float*)d_in[3];
  const unsigned char* mask = (const unsigned char*)d_in[4];
  const float* c1w = (const float*)d_in[5];
  const float* c1b = (const float*)d_in[6];
  const float* g1  = (const float*)d_in[7];
  const float* b1  = (const float*)d_in[8];
  const float* c2w = (const float*)d_in[9];
  const float* c2b = (const float*)d_in[10];
  const float* g2  = (const float*)d_in[11];
  const float* b2  = (const float*)d_in[12];
  const float* lw  = (const float*)d_in[13];
  const float* lb  = (const float*)d_in[14];

  float* x_up   = (float*)d_out;
  float* ldp    = x_up + (size_t)Bn * MAXMEL * CIN1;
  float* emb_up = ldp + (size_t)Bn * Tn;

  // ws layout: idx 256KB | h1 4MB | w1 1.31MB | w2 0.66MB  (~6.2MB)
  int* idx = (int*)d_ws;
  ushort_t* h1 = (ushort_t*)((char*)d_ws + (size_t)Bn * MAXMEL * 4);
  ushort_t* w1 = h1 + (size_t)NROWS * 256;
  ushort_t* w2 = w1 + (size_t)5 * 512 * 256;

  prep_kernel<<<256, 512, 0, stream>>>(c1w, c2w, w1, w2, dur, idx);
  conv1_gather_kernel<<<1280, 256, 0, stream>>>(
      x_res, w1, c1b, g1, b1, h1, x, idx, x_up);
  conv2_gather_kernel<<<1280, 256, 0, stream>>>(
      h1, w2, c2b, g2, b2, lw, lb, mask, ldp, emb, idx, emb_up);
}

// Round 6
// 339.780 us; speedup vs baseline: 1.7270x; 1.0451x over previous
//
#include <hip/hip_runtime.h>

// LengthAdaptor: B=16, T=512, C_IN=512, C_HID=256, C_EMB=384, K=5, MAX_DUR=8
// Outputs (concat, f32): x_up [16,4096,512] | ldp [16,512] | emb_up [16,4096,384]
//
// R15: R12 structure verbatim (5 dispatches, proven best 343us; every fusion
// variant R10/R11/R13/R14 regressed). In-place micro-opts only:
//  (a) staging loads widened: conv1 float4 (was float2), conv2 uint2 (was
//      u32); 5 half-masked iters instead of 9 -- same LDS image (swizzle
//      XOR bits sit above the 8B write word), half the issue count.
//  (b) gathers unrolled x8 (was x4): 8 gathered loads in flight/thread.
// Grid, launch bounds, interleave, LN kernels, prep: verbatim R12.

constexpr int Bn = 16, Tn = 512, CIN1 = 512, CHID = 256, CEMB = 384, MAXMEL = 4096;
constexpr int NROWS = Bn * Tn;
#define LRELU 0.3f
#define EPSV 1e-5f

typedef __attribute__((ext_vector_type(8))) short bf16x8;
typedef __attribute__((ext_vector_type(4))) float f32x4;
typedef __attribute__((ext_vector_type(16))) float f32x16;
typedef __attribute__((ext_vector_type(4))) unsigned int u32x4;
typedef unsigned short ushort_t;

static __device__ __forceinline__ ushort_t f2bf(float f) {
  unsigned u = __builtin_bit_cast(unsigned, f);
  unsigned r = (u + 0x7fffu + ((u >> 16) & 1u)) >> 16;  // RNE
  return (ushort_t)r;
}

// ---------------------------------------------------------------------------
// Conv MFMA body (32x32x16). Block tile 32 rows x 128 cols, 4 waves, each one
// 32x32 acc chain. A staged per 128-ci chunk in LDS (XOR swizzle); B direct
// from L2 (fragment-contiguous). Staging: issue-early, 16B/8B units (R15a).
// ---------------------------------------------------------------------------
template <int CI, bool F32IN>
static __device__ __forceinline__ void conv_body(
    int mt, int ns,
    const float* __restrict__ xin, const ushort_t* __restrict__ inbf,
    const ushort_t* __restrict__ wB, float* __restrict__ hraw) {
  constexpr int NCHUNK = CI / 128;
  constexpr int ROWS = 36, LDSTRIDE = 136;
  __shared__ ushort_t sA[ROWS * LDSTRIDE];

  const int b = mt >> 4, t0 = (mt & 15) * 32;
  const int tid = threadIdx.x;
  const int l = tid & 63, nh = tid >> 6;
  const int lm = l & 31, lq = l >> 5;
  const int cob32 = ns * 4 + nh;

  f32x16 acc;
#pragma unroll
  for (int i = 0; i < 16; ++i) acc[i] = 0.f;

  const ushort_t* pB = wB + (size_t)cob32 * 512 + l * 8;

#pragma unroll 1
  for (int chunk = 0; chunk < NCHUNK; ++chunk) {
    {
      const int cibase = chunk * 128;
      // 1152 units of 4 elems (float4 f32 / uint2 bf16); 5 iters, last half.
      float4 rf[5];
      uint2 ru[5];
      // issue phase: all loads in flight
#pragma unroll
      for (int i = 0; i < 5; ++i) {
        const int p = i * 256 + tid;
        if (p < 1152) {
          const int r = p >> 5;              // 32 units per row
          const int c4 = (p & 31) * 4;       // elem index within row (0..124)
          const int t = t0 - 2 + r;
          if (F32IN) {
            rf[i] = make_float4(0.f, 0.f, 0.f, 0.f);
            if ((unsigned)t < (unsigned)Tn)
              rf[i] = *(const float4*)(xin + (size_t)(b * Tn + t) * CI + cibase + c4);
          } else {
            ru[i] = make_uint2(0u, 0u);
            if ((unsigned)t < (unsigned)Tn)
              ru[i] = *(const uint2*)(inbf + (size_t)(b * Tn + t) * CI + cibase + c4);
          }
        }
      }
      // write phase: cvt + swizzled LDS write (8B words; swizzle XOR bits 3-4
      // of ushort index sit above the 4-ushort word -> same image as R12)
#pragma unroll
      for (int i = 0; i < 5; ++i) {
        const int p = i * 256 + tid;
        if (p < 1152) {
          const int r = p >> 5;
          const int c4 = (p & 31) * 4;
          uint2 hv;
          if (F32IN) {
            hv.x = (unsigned)f2bf(rf[i].x) | ((unsigned)f2bf(rf[i].y) << 16);
            hv.y = (unsigned)f2bf(rf[i].z) | ((unsigned)f2bf(rf[i].w) << 16);
          } else {
            hv = ru[i];
          }
          const int sw = ((r >> 3) & 3) << 3;
          *(uint2*)&sA[r * LDSTRIDE + (c4 ^ sw)] = hv;
        }
      }
    }
    __syncthreads();

#pragma unroll 1
    for (int ksh = 0; ksh < 5; ++ksh) {
      const int r = lm + ksh;
      const int sw = ((r >> 3) & 3) << 3;
      const size_t bbase = (size_t)((ksh * (CI / 16) + chunk * 8) * 8) * 512;
#pragma unroll
      for (int kk = 0; kk < 8; ++kk) {
        const int c = (kk * 16 + lq * 8) ^ sw;
        const bf16x8 a = *(const bf16x8*)&sA[r * LDSTRIDE + c];
        const bf16x8 bv = *(const bf16x8*)(pB + bbase + (size_t)kk * 8 * 512);
        acc = __builtin_amdgcn_mfma_f32_32x32x16_bf16(a, bv, acc, 0, 0, 0);
      }
    }
    __syncthreads();
  }

  // D: col = lane&31, row = (reg&3) + 8*(reg>>2) + 4*(lane>>5)
  const int col = ns * 128 + nh * 32 + lm;
  float* pOut = hraw + (size_t)(b * Tn + t0) * 256 + col;
#pragma unroll
  for (int reg = 0; reg < 16; ++reg) {
    const int row = (reg & 3) + 8 * (reg >> 2) + 4 * lq;
    pOut[(size_t)row * 256] = acc[reg];
  }
}

// ---------------------------------------------------------------------------
// Dispatch 2: conv1 (blk%3==0, 512 blocks) + x_up gather (1024 blocks).
// Grid 1536. Gather unrolled x8 (R15b).
// ---------------------------------------------------------------------------
__global__ __launch_bounds__(256, 2) void conv1_gather_kernel(
    const float* __restrict__ x_res, const ushort_t* __restrict__ w1,
    float* __restrict__ hraw,
    const float* __restrict__ x, const int* __restrict__ idx,
    float* __restrict__ x_up) {
  const int blk = blockIdx.x;
  if (blk % 3 == 0) {
    const int cid = blk / 3;              // 0..511
    conv_body<512, true>(cid & 255, cid >> 8, x_res, nullptr, w1, hraw);
    return;
  }
  // ---- x_up gather: 1024 blocks, 8,388,608 f32x4 units = 32 iters exact ----
  const int gid = blk - 1 - blk / 3;      // 0..1023
  const f32x4* x4 = (const f32x4*)x;
  f32x4* xu4 = (f32x4*)x_up;
  const int tid0 = gid * 256 + threadIdx.x;
  constexpr int stride = 1024 * 256;
  const f32x4 z = (f32x4){0.f, 0.f, 0.f, 0.f};
#pragma unroll 1
  for (int k0 = 0; k0 < 32; k0 += 8) {
    int tv[8];
#pragma unroll
    for (int j = 0; j < 8; ++j)
      tv[j] = idx[(tid0 + (k0 + j) * stride) >> 7];
    f32x4 v[8];
#pragma unroll
    for (int j = 0; j < 8; ++j) {
      const int u = tid0 + (k0 + j) * stride;
      const int i = u & 127;
      const int b = u >> 19;              // (u>>7)>>12
      v[j] = (tv[j] >= 0) ? x4[((b << 9) + tv[j]) * 128 + i] : z;
    }
#pragma unroll
    for (int j = 0; j < 8; ++j)
      __builtin_nontemporal_store(v[j], &xu4[tid0 + (k0 + j) * stride]);
  }
}

// ---------------------------------------------------------------------------
// Dispatch 4: conv2 (blk%3==0, 512 blocks) + emb_up gather (1024 blocks).
// Gather unrolled x8 (R15b).
// ---------------------------------------------------------------------------
__global__ __launch_bounds__(256, 2) void conv2_gather_kernel(
    const ushort_t* __restrict__ h1, const ushort_t* __restrict__ w2,
    float* __restrict__ hraw,
    const float* __restrict__ emb, const int* __restrict__ idx,
    float* __restrict__ emb_up) {
  const int blk = blockIdx.x;
  if (blk % 3 == 0) {
    const int cid = blk / 3;
    conv_body<256, false>(cid & 255, cid >> 8, nullptr, h1, w2, hraw);
    return;
  }
  // ---- emb_up gather: 1024 blocks, 6,291,456 f32x4 units = 24 iters exact ----
  const int gid = blk - 1 - blk / 3;
  const f32x4* e4 = (const f32x4*)emb;
  f32x4* eu4 = (f32x4*)emb_up;
  const int tid0 = gid * 256 + threadIdx.x;
  constexpr int stride = 1024 * 256;
  const f32x4 z = (f32x4){0.f, 0.f, 0.f, 0.f};
#pragma unroll 1
  for (int k0 = 0; k0 < 24; k0 += 8) {
    int tv[8];
    int bp[8];
#pragma unroll
    for (int j = 0; j < 8; ++j) {
      const int u = tid0 + (k0 + j) * stride;
      bp[j] = u / 96;
      tv[j] = idx[bp[j]];
    }
    f32x4 v[8];
#pragma unroll
    for (int j = 0; j < 8; ++j) {
      const int u = tid0 + (k0 + j) * stride;
      const int i = u - bp[j] * 96;
      const int b = bp[j] >> 12;
      v[j] = (tv[j] >= 0) ? e4[((b << 9) + tv[j]) * 96 + i] : z;
    }
#pragma unroll
    for (int j = 0; j < 8; ++j)
      __builtin_nontemporal_store(v[j], &eu4[tid0 + (k0 + j) * stride]);
  }
}

// ---------------------------------------------------------------------------
// bias + leaky-relu + LayerNorm. One wave per row, grid 2048. Verbatim R12.
// FINAL=false: emit h1 bf16. FINAL=true: fused linear(256->1) + mask -> ldp.
// ---------------------------------------------------------------------------
template <bool FINAL>
__global__ __launch_bounds__(256) void ln_kernel(
    const float* __restrict__ hraw,       // [8192][256] f32
    const float* __restrict__ bias, const float* __restrict__ g,
    const float* __restrict__ be, ushort_t* __restrict__ h1,
    const float* __restrict__ lw, const float* __restrict__ lb,
    const unsigned char* __restrict__ mask, float* __restrict__ ldp) {
  const int row = blockIdx.x * 4 + (threadIdx.x >> 6);
  const int l = threadIdx.x & 63;
  const f32x4 p = ((const f32x4*)hraw)[row * 64 + l];
  const f32x4 bi = ((const f32x4*)bias)[l];
  float v0 = p.x + bi.x, v1 = p.y + bi.y, v2 = p.z + bi.z, v3 = p.w + bi.w;
  v0 = (v0 > 0.f) ? v0 : LRELU * v0;
  v1 = (v1 > 0.f) ? v1 : LRELU * v1;
  v2 = (v2 > 0.f) ? v2 : LRELU * v2;
  v3 = (v3 > 0.f) ? v3 : LRELU * v3;
  float s = v0 + v1 + v2 + v3;
  float s2 = v0 * v0 + v1 * v1 + v2 * v2 + v3 * v3;
#pragma unroll
  for (int off = 32; off >= 1; off >>= 1) {
    s += __shfl_xor(s, off);
    s2 += __shfl_xor(s2, off);
  }
  const float mu = s * (1.f / 256.f);
  const float var = s2 * (1.f / 256.f) - mu * mu;
  const float rs = rsqrtf(var + EPSV);
  const f32x4 gg = ((const f32x4*)g)[l];
  const f32x4 bb = ((const f32x4*)be)[l];
  const float h0 = (v0 - mu) * rs * gg.x + bb.x;
  const float h1v = (v1 - mu) * rs * gg.y + bb.y;
  const float h2 = (v2 - mu) * rs * gg.z + bb.z;
  const float h3 = (v3 - mu) * rs * gg.w + bb.w;
  if (!FINAL) {
    ushort4 uh;
    uh.x = f2bf(h0); uh.y = f2bf(h1v); uh.z = f2bf(h2); uh.w = f2bf(h3);
    ((ushort4*)h1)[row * 64 + l] = uh;
  } else {
    const f32x4 lv = ((const f32x4*)lw)[l];
    float d = h0 * lv.x + h1v * lv.y + h2 * lv.z + h3 * lv.w;
#pragma unroll
    for (int off = 32; off >= 1; off >>= 1) d += __shfl_xor(d, off);
    if (l == 0) {
      float val = d + lb[0];
      if (mask[row]) val = 0.f;
      ldp[row] = val;
    }
  }
}

// ---------------------------------------------------------------------------
// Dispatch 1: weight prep (blocks 0..239, 8 frags/block) + build_idx
// (blocks 240..255). 512 threads. Verbatim R12.
// ---------------------------------------------------------------------------
__global__ __launch_bounds__(512) void prep_kernel(
    const float* __restrict__ w1src, const float* __restrict__ w2src,
    ushort_t* __restrict__ w1dst, ushort_t* __restrict__ w2dst,
    const int* __restrict__ dur, int* __restrict__ idx) {
  __shared__ int wsum[8];
  const int blk = blockIdx.x;
  const int tid = threadIdx.x;
  if (blk < 240) {
    const float* src;
    ushort_t* dst;
    int CI, fr, sh;
    const int wv = tid >> 6, l = tid & 63;
    if (blk < 160) { src = w1src; dst = w1dst; CI = 512; sh = 5; fr = blk * 8 + wv; }
    else           { src = w2src; dst = w2dst; CI = 256; sh = 4; fr = (blk - 160) * 8 + wv; }
    const int cob32 = fr & 7;
    const int t = fr >> 3;
    const int ksh = t >> sh;
    const int ci16 = t & ((1 << sh) - 1);
    const int ci = ci16 * 16 + (l >> 5) * 8;
    const int co = cob32 * 32 + (l & 31);
    ushort_t v[8];
#pragma unroll
    for (int j = 0; j < 8; ++j)
      v[j] = f2bf(src[((size_t)(ksh * CI + ci + j)) * 256 + co]);
    u32x4 pack;
#pragma unroll
    for (int q = 0; q < 4; ++q)
      pack[q] = (unsigned)v[q * 2] | ((unsigned)v[q * 2 + 1] << 16);
    *(u32x4*)&dst[(size_t)fr * 512 + l * 8] = pack;
    return;
  }
  // ---- build_idx path ----
  const int b = blk - 240;
  const int lane = tid & 63, wv = tid >> 6;
  const int d = dur[b * Tn + tid];
  int v = d;
#pragma unroll
  for (int off = 1; off <= 32; off <<= 1) {
    const int t = __shfl_up(v, off);
    if (lane >= off) v += t;
  }
  if (lane == 63) wsum[wv] = v;
  __syncthreads();
  int woff = 0, total = 0;
#pragma unroll
  for (int i = 0; i < 8; ++i) {
    const int s = wsum[i];
    if (i < wv) woff += s;
    total += s;
  }
  const int end = v + woff;               // inclusive cumsum
  for (int p = end - d; p < end; ++p) idx[b * MAXMEL + p] = tid;
  for (int p = total + tid; p < MAXMEL; p += 512) idx[b * MAXMEL + p] = -1;
}

// ---------------------------------------------------------------------------
extern "C" void kernel_launch(void* const* d_in, const int* in_sizes, int n_in,
                              void* d_out, int out_size, void* d_ws, size_t ws_size,
                              hipStream_t stream) {
  const float* x     = (const float*)d_in[0];
  const float* x_res = (const float*)d_in[1];
  const int*   dur   = (const int*)d_in[2];
  const float* emb   = (const float*)d_in[3];
  const unsigned char* mask = (const unsigned char*)d_in[4];
  const float* c1w = (const float*)d_in[5];
  const float* c1b = (const float*)d_in[6];
  const float* g1  = (const float*)d_in[7];
  const float* b1  = (const float*)d_in[8];
  const float* c2w = (const float*)d_in[9];
  const float* c2b = (const float*)d_in[10];
  const float* g2  = (const float*)d_in[11];
  const float* b2  = (const float*)d_in[12];
  const float* lw  = (const float*)d_in[13];
  const float* lb  = (const float*)d_in[14];

  float* x_up   = (float*)d_out;
  float* ldp    = x_up + (size_t)Bn * MAXMEL * CIN1;
  float* emb_up = ldp + (size_t)Bn * Tn;

  // ws layout: idx 256KB | h1 4MB | w1 1.31MB | w2 0.66MB | hraw 8MB ≈ 14.5MB
  int* idx = (int*)d_ws;
  ushort_t* h1 = (ushort_t*)((char*)d_ws + (size_t)Bn * MAXMEL * 4);
  ushort_t* w1 = h1 + (size_t)NROWS * 256;
  ushort_t* w2 = w1 + (size_t)5 * 512 * 256;
  float* hraw = (float*)(w2 + (size_t)5 * 256 * 256);

  prep_kernel<<<256, 512, 0, stream>>>(c1w, c2w, w1, w2, dur, idx);
  conv1_gather_kernel<<<1536, 256, 0, stream>>>(
      x_res, w1, hraw, x, idx, x_up);
  ln_kernel<false><<<NROWS / 4, 256, 0, stream>>>(
      hraw, c1b, g1, b1, h1, nullptr, nullptr, nullptr, nullptr);
  conv2_gather_kernel<<<1536, 256, 0, stream>>>(
      h1, w2, hraw, emb, idx, emb_up);
  ln_kernel<true><<<NROWS / 4, 256, 0, stream>>>(
      hraw, c2b, g2, b2, nullptr, lw, lb, mask, ldp);
}